// Round 8
// baseline (165.074 us; speedup 1.0000x reference)
//
#include <hip/hip_runtime.h>

typedef float v2f __attribute__((ext_vector_type(2)));
typedef __fp16 h2v __attribute__((ext_vector_type(2)));
typedef __fp16 h4v __attribute__((ext_vector_type(4)));

#define BLK 256
#define BATCH 8192

// ---- packed fp32 math (hipcc scalarizes v2f ops; force VOP3P) ----
__device__ __forceinline__ v2f pk_mul(v2f a, v2f b) {
  v2f d;
  asm("v_pk_mul_f32 %0, %1, %2" : "=v"(d) : "v"(a), "v"(b));
  return d;
}
__device__ __forceinline__ v2f pk_fma(v2f a, v2f b, v2f c) {
  v2f d;
  asm("v_pk_fma_f32 %0, %1, %2, %3" : "=v"(d) : "v"(a), "v"(b), "v"(c));
  return d;
}

// ================= GF(2) 12x12 compile-time machinery =================
struct M12 { unsigned r[12]; };

constexpr M12 mp_matrix() {
  // CNOT-ring permutation y = P x (verified rounds 1-6):
  // y_p = x_p ^ ... ^ x_11 (p<=10); y_11 = x_0 ^ ... ^ x_10
  M12 m{};
  for (int p = 0; p <= 10; ++p) m.r[p] = (0xFFFu >> p) << p;
  m.r[11] = 0x7FFu;
  return m;
}
constexpr M12 MP = mp_matrix();

constexpr unsigned mv(const M12 m, unsigned v) {   // y = M v
  unsigned y = 0;
  for (int p = 0; p < 12; ++p)
    y |= (unsigned)(__builtin_popcount(m.r[p] & v) & 1) << p;
  return y;
}
constexpr M12 mmul(const M12 a, const M12 b) {     // c(x) = a(b(x))
  M12 c{};
  for (int p = 0; p < 12; ++p) {
    unsigned acc = 0;
    for (int q = 0; q < 12; ++q)
      if ((a.r[p] >> q) & 1u) acc ^= b.r[q];
    c.r[p] = acc;
  }
  return c;
}
constexpr M12 minv(const M12 a0) {                 // Gauss-Jordan over GF(2)
  unsigned a[12] = {}, v[12] = {};
  for (int i = 0; i < 12; ++i) { a[i] = a0.r[i]; v[i] = 1u << i; }
  for (int c = 0; c < 12; ++c) {
    int piv = c;
    while (!((a[piv] >> c) & 1u)) ++piv;
    unsigned ta = a[piv], tv = v[piv];
    a[piv] = a[c]; v[piv] = v[c]; a[c] = ta; v[c] = tv;
    for (int r2 = 0; r2 < 12; ++r2)
      if (r2 != c && ((a[r2] >> c) & 1u)) { a[r2] ^= a[c]; v[r2] ^= v[c]; }
  }
  M12 out{};
  for (int i = 0; i < 12; ++i) out.r[i] = v[i];
  return out;
}
constexpr unsigned colq(const M12 m, int q) {
  unsigned c = 0;
  for (int p = 0; p < 12; ++p) c |= ((m.r[p] >> q) & 1u) << p;
  return c;
}
constexpr M12 from_cols(const unsigned (&c)[12]) {
  M12 m{};
  for (int p = 0; p < 12; ++p) {
    unsigned row = 0;
    for (int j = 0; j < 12; ++j) row |= ((c[j] >> p) & 1u) << j;
    m.r[p] = row;
  }
  return m;
}
constexpr M12 mk_id() { M12 m{}; for (int p = 0; p < 12; ++p) m.r[p] = 1u << p; return m; }
constexpr M12 MID = mk_id();
constexpr M12 MPI = minv(MP);

constexpr bool meq(const M12 a, const M12 b) {
  for (int p = 0; p < 12; ++p) if (a.r[p] != b.r[p]) return false;
  return true;
}
static_assert(meq(mmul(MP, MPI), MID), "P inverse");

struct Frame { M12 A, Ai; };
constexpr Frame FID{MID, MID};
constexpr Frame absorb(const Frame f) { return Frame{ mmul(MP, f.A), mmul(f.Ai, MPI) }; }
constexpr Frame apply_tau(const Frame f, const M12 t) {
  return Frame{ mmul(f.A, minv(t)), mmul(t, f.Ai) };
}

constexpr void complete12(unsigned (&V)[12], int n) {
  unsigned ech[12] = {};
  for (int i = 0; i < n; ++i) {
    unsigned x = V[i];
    for (int bb = 11; bb >= 0; --bb) {
      if (((x >> bb) & 1u) == 0u) continue;
      if (ech[bb]) { x ^= ech[bb]; }
      else { ech[bb] = x; break; }
    }
  }
  int cnt = n;
  for (unsigned j = 0; j < 12 && cnt < 12; ++j) {
    unsigned x = 1u << j;
    bool placed = false;
    for (int bb = 11; bb >= 0 && !placed; --bb) {
      if (((x >> bb) & 1u) == 0u) continue;
      if (ech[bb]) { x ^= ech[bb]; }
      else { ech[bb] = x; placed = true; }
    }
    if (placed) { V[cnt] = 1u << j; ++cnt; }
  }
}
constexpr M12 make_tau(const Frame f, const int* qs, const unsigned* tg, int n) {
  unsigned S[12] = {}, D[12] = {};
  for (int i = 0; i < n; ++i) { S[i] = colq(f.Ai, qs[i]); D[i] = tg[i]; }
  complete12(S, n); complete12(D, n);
  return mmul(from_cols(D), minv(from_cols(S)));
}
constexpr bool chk_group(const Frame f, const int* qs, const unsigned* tg, int n) {
  for (int i = 0; i < n; ++i) if (colq(f.Ai, qs[i]) != tg[i]) return false;
  return true;
}

// groups: 4 logical qubits -> local-index targets {8,4,2,1} (bit0 = pack)
constexpr int QA[4] = {11, 10, 9, 8};
constexpr int QB[4] = {7, 6, 5, 4};
constexpr int QC[4] = {3, 2, 1, 0};
constexpr unsigned T4[4] = {8u, 4u, 2u, 1u};

constexpr Frame F1  = absorb(FID);                 // ring 1 absorbed
constexpr M12  S2a = make_tau(F1,  QA, T4, 4);
constexpr Frame F2a = apply_tau(F1, S2a);
constexpr M12  S2b = make_tau(F2a, QB, T4, 4);
constexpr Frame F2b = apply_tau(F2a, S2b);
constexpr M12  S2c = make_tau(F2b, QC, T4, 4);
constexpr Frame F2c = apply_tau(F2b, S2c);
constexpr Frame F3  = absorb(F2c);                 // ring 2 absorbed
constexpr M12  S3a = make_tau(F3,  QA, T4, 4);
constexpr Frame F3a = apply_tau(F3, S3a);
constexpr M12  S3b = make_tau(F3a, QB, T4, 4);
constexpr Frame F3b = apply_tau(F3a, S3b);
constexpr M12  S3c = make_tau(F3b, QC, T4, 4);
constexpr Frame F3c = apply_tau(F3b, S3c);
constexpr Frame F4  = absorb(F3c);                 // ring 3 absorbed; measure frame

static_assert(chk_group(F2a, QA, T4, 4), "G2a");
static_assert(chk_group(F2b, QB, T4, 4), "G2b");
static_assert(chk_group(F2c, QC, T4, 4), "G2c");
static_assert(chk_group(F3a, QA, T4, 4), "G3a");
static_assert(chk_group(F3b, QB, T4, 4), "G3b");
static_assert(chk_group(F3c, QC, T4, 4), "G3c");

// ---- per-pass LDS layout bijection B = I + (lane bits -> bank-bit masks) ----
// B(e_{4+k}) = e_{4+k} ^ d[k], d[k] subset of addr bits [4:1] (d[0]: [3:1]).
// Unipotent (N^2 = 0) -> invertible. Identity on locals (bits 3..0) + waves.
struct DTup { unsigned d[6]; };

constexpr unsigned bapp(const DTup& dt, unsigned v) {
  unsigned o = v;
  for (int k = 0; k < 6; ++k)
    if ((v >> (4 + k)) & 1u) o ^= dt.d[k];
  return o;
}
// rank over the 5 bank bits [4:0] of up-to-6 pre-masked values
constexpr int rank5(const unsigned* v, int n) {
  unsigned basis[5] = {};
  int r = 0;
  for (int i = 0; i < n; ++i) {
    unsigned x = v[i];
    for (int b = 4; b >= 0; --b) {
      if (!((x >> b) & 1u)) continue;
      if (basis[b]) { x ^= basis[b]; }
      else { basis[b] = x; ++r; break; }
    }
  }
  return r;
}
constexpr int rrank(const DTup& dt) {   // read side: b64 bank-pair bits [4:1]
  unsigned v[6] = {};
  for (int k = 0; k < 6; ++k) v[k] = bapp(dt, 1u << (4 + k)) & 0x1Eu;
  return rank5(v, 6);
}
constexpr int wrank(const DTup& dt, const unsigned* t) {  // write: bits [4:0]
  unsigned v[6] = {};
  for (int k = 0; k < 6; ++k) v[k] = bapp(dt, t[k]) & 0x1Fu;
  return rank5(v, 6);
}
// Deterministic greedy: seed read-safe (d1,d2,d3 = 2,4,8 -> read rank 4),
// then sweep positions improving write rank under hard read-rank-4 constraint.
constexpr DTup find_swz(const M12 T) {
  unsigned t[6] = {};
  for (int k = 0; k < 6; ++k) t[k] = mv(T, 1u << (4 + k));
  DTup dt{{0u, 2u, 4u, 8u, 0u, 0u}};
  int bestw = wrank(dt, t);
  for (int sweep = 0; sweep < 2; ++sweep) {
    for (int k = 0; k < 6; ++k) {
      unsigned bestv = dt.d[k];
      for (unsigned v = 0; v < 16; ++v) {
        const unsigned cand = v << 1;
        if (k == 0 && (cand & 0x10u)) continue;   // d0 limited to bits [3:1]
        dt.d[k] = cand;
        if (rrank(dt) != 4) continue;
        const int wr = wrank(dt, t);
        if (wr > bestw) { bestw = wr; bestv = cand; }
      }
      dt.d[k] = bestv;
    }
  }
  return dt;
}
// one top-level constexpr evaluation per tau (bounded step budget each)
constexpr DTup D2a = find_swz(S2a);
constexpr DTup D2b = find_swz(S2b);
constexpr DTup D2c = find_swz(S2c);
constexpr DTup D3a = find_swz(S3a);
constexpr DTup D3b = find_swz(S3b);
constexpr DTup D3c = find_swz(S3c);
static_assert(rrank(D2a) == 4 && rrank(D2b) == 4 && rrank(D2c) == 4 &&
              rrank(D3a) == 4 && rrank(D3b) == 4 && rrank(D3c) == 4,
              "read swizzle rank");

struct TauRT {
  unsigned wc[16];            // write offsets B(T(j)), j local
  unsigned cb[6], cw[2];      // write base contributions B(T(lane/wave bit))
  unsigned rcb[6], rcw[2];    // read  base contributions B(lane/wave bit)
};
constexpr TauRT mk_rt(const M12 T, const DTup dt) {
  TauRT t{};
  for (unsigned j = 0; j < 16; ++j) t.wc[j] = bapp(dt, mv(T, j));
  for (int k = 0; k < 6; ++k) {
    t.cb[k]  = bapp(dt, mv(T, 1u << (4 + k)));
    t.rcb[k] = bapp(dt, 1u << (4 + k));
  }
  for (int j = 0; j < 2; ++j) {
    t.cw[j]  = bapp(dt, mv(T, 1u << (10 + j)));
    t.rcw[j] = bapp(dt, 1u << (10 + j));
  }
  return t;
}
constexpr TauRT RT[6] = { mk_rt(S2a, D2a), mk_rt(S2b, D2b), mk_rt(S2c, D2c),
                          mk_rt(S3a, D3a), mk_rt(S3b, D3b), mk_rt(S3c, D3c) };

// ================= device primitives =================
// sigma: amp at position p moves to tau(p); block-wide f16x2 LDS staging.
template<int TI>
__device__ __forceinline__ void sigma_pass(v2f (&xr)[8], v2f (&xi)[8],
                                           unsigned* sb, const int lane,
                                           const int w) {
  unsigned wb = 0u, rb = 0u;
  #pragma unroll
  for (int k = 0; k < 6; ++k) {
    const bool on = ((lane >> k) & 1) != 0;
    wb ^= on ? RT[TI].cb[k]  : 0u;
    rb ^= on ? RT[TI].rcb[k] : 0u;
  }
  wb ^= (w & 1) ? RT[TI].cw[0] : 0u;
  rb ^= (w & 1) ? RT[TI].rcw[0] : 0u;
  wb ^= (w & 2) ? RT[TI].cw[1] : 0u;
  rb ^= (w & 2) ? RT[TI].rcw[1] : 0u;
  h2v* sh = (h2v*)sb;
  #pragma unroll
  for (int p = 0; p < 8; ++p) {
    sh[wb ^ RT[TI].wc[2 * p]]     = __builtin_amdgcn_cvt_pkrtz(xr[p].x, xi[p].x);
    sh[wb ^ RT[TI].wc[2 * p + 1]] = __builtin_amdgcn_cvt_pkrtz(xr[p].y, xi[p].y);
  }
  __syncthreads();
  #pragma unroll
  for (int p = 0; p < 8; ++p) {
    const h4v hv = *(const h4v*)(sb + (rb ^ (unsigned)(2 * p)));
    xr[p] = (v2f){(float)hv[0], (float)hv[2]};
    xi[p] = (v2f){(float)hv[1], (float)hv[3]};
  }
  __syncthreads();
}

// register gate; fused gate G = [[g, -conj(h)], [h, conj(g)]], gh=(gr,gi,hr,hi).
// Packed fp32 throughout.
template<unsigned MASK, unsigned RROW>
__device__ __forceinline__ void gate_apply(v2f (&xr)[8], v2f (&xi)[8],
                                           const unsigned pbase,
                                           const float4 gh) {
  static_assert((__builtin_popcount(MASK & RROW) & 1) == 1, "role/mask dot");
  constexpr unsigned R4 = RROW & 15u;
  constexpr bool FLIP = (R4 & 1u) != 0u;
  const int hl = __popc(pbase & (RROW & 0xFF0u)) & 1;
  const float sgn = hl ? -1.f : 1.f;
  const float egs = gh.y * sgn, ehs = gh.z * sgn;
  const v2f Vgr = (v2f){gh.x, gh.x};
  const v2f Vhi = (v2f){gh.w, gh.w};
  const v2f Mhi = (v2f){-gh.w, -gh.w};
  const v2f Eg  = (v2f){ egs, FLIP ? -egs :  egs};
  const v2f Meg = (v2f){-egs, FLIP ?  egs : -egs};
  const v2f Eh  = (v2f){ ehs, FLIP ? -ehs :  ehs};
  const v2f Meh = (v2f){-ehs, FLIP ?  ehs : -ehs};

  if constexpr (MASK == 1u) {
    static_assert(FLIP, "bit0 gate needs role bit0");
    #pragma unroll
    for (int p = 0; p < 8; ++p) {
      const int sp = __builtin_popcount((unsigned)p & (R4 >> 1)) & 1;
      const v2f EgP = sp ? Meg : Eg, MegP = sp ? Eg : Meg;
      const v2f MehP = sp ? Eh : Meh;
      const v2f ar = xr[p], ai = xi[p];
      const v2f br = __builtin_shufflevector(ar, ar, 1, 0);
      const v2f bi = __builtin_shufflevector(ai, ai, 1, 0);
      v2f t0 = pk_mul(Vgr, ar);
      t0 = pk_fma(MegP, ai, t0);
      t0 = pk_fma(MehP, br, t0);
      xr[p] = pk_fma(Mhi, bi, t0);
      v2f t1 = pk_mul(Vgr, ai);
      t1 = pk_fma(EgP, ar, t1);
      t1 = pk_fma(MehP, bi, t1);
      xi[p] = pk_fma(Vhi, br, t1);
    }
  } else {
    constexpr int MB = (int)(MASK >> 1);
    #pragma unroll
    for (int p = 0; p < 8; ++p) {
      if ((p & MB) == 0) {
        const int q = p | MB;
        const int sp = __builtin_popcount((unsigned)p & (R4 >> 1)) & 1;
        const v2f EgP = sp ? Meg : Eg, MegP = sp ? Eg : Meg;
        const v2f EhP = sp ? Meh : Eh, MehP = sp ? Eh : Meh;
        const v2f arP = xr[p], aiP = xi[p], arQ = xr[q], aiQ = xi[q];
        v2f t0 = pk_mul(Vgr, arP);
        t0 = pk_fma(MegP, aiP, t0);
        t0 = pk_fma(MehP, arQ, t0);
        xr[p] = pk_fma(Mhi, aiQ, t0);
        v2f t1 = pk_mul(Vgr, aiP);
        t1 = pk_fma(EgP, arP, t1);
        t1 = pk_fma(MehP, aiQ, t1);
        xi[p] = pk_fma(Vhi, arQ, t1);
        v2f t2 = pk_mul(Vgr, arQ);
        t2 = pk_fma(EgP, aiQ, t2);
        t2 = pk_fma(EhP, arP, t2);
        xr[q] = pk_fma(Mhi, aiP, t2);
        v2f t3 = pk_mul(Vgr, aiQ);
        t3 = pk_fma(MegP, arQ, t3);
        t3 = pk_fma(EhP, aiP, t3);
        xi[q] = pk_fma(Vhi, arP, t3);
      }
    }
  }
}

// ================= kernel: one sample per 256-thread block =================
__global__ __launch_bounds__(BLK, 4) void qsim_kernel(
    const float* __restrict__ sr, const float* __restrict__ si,
    const float* __restrict__ wts, const float* __restrict__ hw,
    const float* __restrict__ hb, float* __restrict__ out) {
  __shared__ __align__(16) unsigned sbuf[4096];  // 16 KB f16x2 sigma staging
  __shared__ float4 gt4[24];                     // fused gates (gr,gi,hr,hi)
  __shared__ float4 qv[12];                      // wire vectors after enc+layer0
  __shared__ float xacc[4];

  const int t = threadIdx.x;
  const int lane = t & 63;
  const int w = t >> 6;                          // wave id = position bits 11..10
  const int s = blockIdx.x;

  // Phase A: fused gate table for ref layers 1,2: g=g00, h=g10
  if (t < 24) {
    const int l = 1 + t / 12, i = t % 12;
    const float a  = wts[(l * 12 + i) * 2 + 0] * 0.5f;
    const float bb = wts[(l * 12 + i) * 2 + 1] * 0.5f;
    float sa, ca, sb2, cb;
    sincosf(a, &sa, &ca);
    sincosf(bb, &sb2, &cb);
    gt4[t] = make_float4(cb * ca, sb2 * sa, sb2 * ca, -cb * sa);
  }
  // Phase B: per-wire vectors q_i = G_layer0 * RY(a)RX(a)|0>
  if (t >= 64 && t < 76) {
    const int i = t - 64;
    const float ang = atan2f(si[(size_t)s * 4096 + i],
                             sr[(size_t)s * 4096 + i]) * 0.5f;
    float sn, cs;
    sincosf(ang, &sn, &cs);
    const float e0r = cs * cs, e0i = sn * sn, e1r = sn * cs, e1i = -sn * cs;
    const float a  = wts[i * 2 + 0] * 0.5f;
    const float bb = wts[i * 2 + 1] * 0.5f;
    float sa, ca, sb2, cb;
    sincosf(a, &sa, &ca);
    sincosf(bb, &sb2, &cb);
    const float g00r = cb * ca,  g00i = sb2 * sa, g01r = -sb2 * ca, g01i = -cb * sa;
    const float g10r = sb2 * ca, g10i = -cb * sa, g11r = cb * ca,   g11i = -sb2 * sa;
    const float q0r = g00r * e0r - g00i * e0i + g01r * e1r - g01i * e1i;
    const float q0i = g00r * e0i + g00i * e0r + g01r * e1i + g01i * e1r;
    const float q1r = g10r * e0r - g10i * e0i + g11r * e1r - g11i * e1i;
    const float q1i = g10r * e0i + g10i * e0r + g11r * e1i + g11i * e1r;
    qv[i] = make_float4(q0r, q0i, q1r, q1i);
  }
  __syncthreads();

  // Phase C: product state. wire0<->bit11(w>>1), wire1<->bit10(w&1),
  // wires2-7<->lane bits 5..0, wires8-11<->local bits 3..0 (bit0 = pack).
  v2f xr[8], xi[8];
  {
    const float4* q = qv;
    float Lr, Li;
    { const float4 q0 = q[0]; const int b0 = (w >> 1) & 1;
      Lr = b0 ? q0.z : q0.x; Li = b0 ? q0.w : q0.y; }
    { const float4 q1 = q[1]; const int b1 = w & 1;
      const float fr = b1 ? q1.z : q1.x, fi = b1 ? q1.w : q1.y;
      const float nr = Lr * fr - Li * fi, ni = Lr * fi + Li * fr;
      Lr = nr; Li = ni; }
    #pragma unroll
    for (int i = 2; i <= 7; ++i) {
      const float4 qq = q[i];
      const int bit = (lane >> (7 - i)) & 1;
      const float fr = bit ? qq.z : qq.x, fi = bit ? qq.w : qq.y;
      const float nr = Lr * fr - Li * fi, ni = Lr * fi + Li * fr;
      Lr = nr; Li = ni;
    }
    float LTr[4], LTi[4];
    { const float4 q8 = q[8], q9 = q[9];
      #pragma unroll
      for (int m = 0; m < 4; ++m) {
        const float ar = (m & 2) ? q8.z : q8.x, ai = (m & 2) ? q8.w : q8.y;
        const float br = (m & 1) ? q9.z : q9.x, bi = (m & 1) ? q9.w : q9.y;
        const float tr = ar * br - ai * bi, ti = ar * bi + ai * br;
        LTr[m] = Lr * tr - Li * ti; LTi[m] = Lr * ti + Li * tr;
      } }
    float tabr[4], tabi[4];
    { const float4 qA = q[10], qB = q[11];
      #pragma unroll
      for (int m = 0; m < 4; ++m) {
        const float ar = (m & 2) ? qA.z : qA.x, ai = (m & 2) ? qA.w : qA.y;
        const float br = (m & 1) ? qB.z : qB.x, bi = (m & 1) ? qB.w : qB.y;
        tabr[m] = ar * br - ai * bi; tabi[m] = ar * bi + ai * br;
      } }
    #pragma unroll
    for (int p = 0; p < 8; ++p) {
      const int m = p >> 1, tb = (p & 1) << 1;
      const v2f Tr = (v2f){tabr[tb], tabr[tb + 1]}, Ti = (v2f){tabi[tb], tabi[tb + 1]};
      const v2f Hr = (v2f){LTr[m], LTr[m]}, Hi = (v2f){LTi[m], LTi[m]};
      xr[p] = Hr * Tr - Hi * Ti;
      xi[p] = Hr * Ti + Hi * Tr;
    }
  }

  const unsigned pbase = ((unsigned)w << 10) | ((unsigned)lane << 4);

  // ======= layer 2 (ring1 pre-absorbed) =======
  sigma_pass<0>(xr, xi, sbuf, lane, w);
  gate_apply<8u, F2a.A.r[11]>(xr, xi, pbase, gt4[0]);
  gate_apply<4u, F2a.A.r[10]>(xr, xi, pbase, gt4[1]);
  gate_apply<2u, F2a.A.r[ 9]>(xr, xi, pbase, gt4[2]);
  gate_apply<1u, F2a.A.r[ 8]>(xr, xi, pbase, gt4[3]);
  sigma_pass<1>(xr, xi, sbuf, lane, w);
  gate_apply<8u, F2b.A.r[ 7]>(xr, xi, pbase, gt4[4]);
  gate_apply<4u, F2b.A.r[ 6]>(xr, xi, pbase, gt4[5]);
  gate_apply<2u, F2b.A.r[ 5]>(xr, xi, pbase, gt4[6]);
  gate_apply<1u, F2b.A.r[ 4]>(xr, xi, pbase, gt4[7]);
  sigma_pass<2>(xr, xi, sbuf, lane, w);
  gate_apply<8u, F2c.A.r[ 3]>(xr, xi, pbase, gt4[8]);
  gate_apply<4u, F2c.A.r[ 2]>(xr, xi, pbase, gt4[9]);
  gate_apply<2u, F2c.A.r[ 1]>(xr, xi, pbase, gt4[10]);
  gate_apply<1u, F2c.A.r[ 0]>(xr, xi, pbase, gt4[11]);
  // ======= layer 3 (ring2 absorbed) =======
  sigma_pass<3>(xr, xi, sbuf, lane, w);
  gate_apply<8u, F3a.A.r[11]>(xr, xi, pbase, gt4[12]);
  gate_apply<4u, F3a.A.r[10]>(xr, xi, pbase, gt4[13]);
  gate_apply<2u, F3a.A.r[ 9]>(xr, xi, pbase, gt4[14]);
  gate_apply<1u, F3a.A.r[ 8]>(xr, xi, pbase, gt4[15]);
  sigma_pass<4>(xr, xi, sbuf, lane, w);
  gate_apply<8u, F3b.A.r[ 7]>(xr, xi, pbase, gt4[16]);
  gate_apply<4u, F3b.A.r[ 6]>(xr, xi, pbase, gt4[17]);
  gate_apply<2u, F3b.A.r[ 5]>(xr, xi, pbase, gt4[18]);
  gate_apply<1u, F3b.A.r[ 4]>(xr, xi, pbase, gt4[19]);
  sigma_pass<5>(xr, xi, sbuf, lane, w);
  gate_apply<8u, F3c.A.r[ 3]>(xr, xi, pbase, gt4[20]);
  gate_apply<4u, F3c.A.r[ 2]>(xr, xi, pbase, gt4[21]);
  gate_apply<2u, F3c.A.r[ 1]>(xr, xi, pbase, gt4[22]);
  gate_apply<1u, F3c.A.r[ 0]>(xr, xi, pbase, gt4[23]);

  // ======= measure: y = sum |amp|^2 * w(F4.A * pos) + bias =======
  float hp[12];
  #pragma unroll
  for (int i = 0; i < 12; ++i) {
    const unsigned R = F4.A.r[11 - i];
    const float h = hw[i];
    hp[i] = (__popc(pbase & (R & 0xFF0u)) & 1) ? -h : h;
  }
  v2f acc = (v2f){0.f, 0.f};
  #pragma unroll
  for (int p = 0; p < 8; ++p) {
    float w0 = 0.f, w1 = 0.f;
    #pragma unroll
    for (int i = 0; i < 12; ++i) {
      const unsigned RL = F4.A.r[11 - i] & 15u;
      w0 += (__builtin_popcount((unsigned)(2 * p) & RL) & 1) ? -hp[i] : hp[i];
      w1 += (__builtin_popcount((unsigned)(2 * p + 1) & RL) & 1) ? -hp[i] : hp[i];
    }
    v2f mag = pk_mul(xr[p], xr[p]);
    mag = pk_fma(xi[p], xi[p], mag);
    acc = pk_fma(mag, (v2f){w0, w1}, acc);
  }
  float accs = acc.x + acc.y;
  #pragma unroll
  for (int off = 1; off < 64; off <<= 1) accs += __shfl_xor(accs, off, 64);

  if (lane == 0) xacc[w] = accs;
  __syncthreads();
  if (t == 0) out[s] = xacc[0] + xacc[1] + xacc[2] + xacc[3] + hb[0];
}

extern "C" void kernel_launch(void* const* d_in, const int* in_sizes, int n_in,
                              void* d_out, int out_size, void* d_ws, size_t ws_size,
                              hipStream_t stream) {
  const float* sr  = (const float*)d_in[0];
  const float* si  = (const float*)d_in[1];
  const float* wts = (const float*)d_in[2];
  const float* hw  = (const float*)d_in[3];
  const float* hb  = (const float*)d_in[4];
  float* out = (float*)d_out;
  qsim_kernel<<<BATCH, BLK, 0, stream>>>(sr, si, wts, hw, hb, out);
}

// Round 9
// 101.665 us; speedup vs baseline: 1.6237x; 1.6237x over previous
//
#include <hip/hip_runtime.h>

typedef __fp16 h2v __attribute__((ext_vector_type(2)));
typedef _Float16 f16x8 __attribute__((ext_vector_type(8)));
typedef float f32x4 __attribute__((ext_vector_type(4)));

#define BLK 256
#define BATCH 8192

// ================= GF(2) 12x12 compile-time machinery =================
struct M12 { unsigned r[12]; };

constexpr M12 mp_matrix() {
  // CNOT-ring permutation y = P x (verified rounds 1-8)
  M12 m{};
  for (int p = 0; p <= 10; ++p) m.r[p] = (0xFFFu >> p) << p;
  m.r[11] = 0x7FFu;
  return m;
}
constexpr M12 MP = mp_matrix();

constexpr unsigned mv(const M12 m, unsigned v) {
  unsigned y = 0;
  for (int p = 0; p < 12; ++p)
    y |= (unsigned)(__builtin_popcount(m.r[p] & v) & 1) << p;
  return y;
}
constexpr M12 mmul(const M12 a, const M12 b) {     // c(x) = a(b(x))
  M12 c{};
  for (int p = 0; p < 12; ++p) {
    unsigned acc = 0;
    for (int q = 0; q < 12; ++q)
      if ((a.r[p] >> q) & 1u) acc ^= b.r[q];
    c.r[p] = acc;
  }
  return c;
}
constexpr M12 minv(const M12 a0) {
  unsigned a[12] = {}, v[12] = {};
  for (int i = 0; i < 12; ++i) { a[i] = a0.r[i]; v[i] = 1u << i; }
  for (int c = 0; c < 12; ++c) {
    int piv = c;
    while (!((a[piv] >> c) & 1u)) ++piv;   // OOB => constexpr error (singular)
    unsigned ta = a[piv], tv = v[piv];
    a[piv] = a[c]; v[piv] = v[c]; a[c] = ta; v[c] = tv;
    for (int r2 = 0; r2 < 12; ++r2)
      if (r2 != c && ((a[r2] >> c) & 1u)) { a[r2] ^= a[c]; v[r2] ^= v[c]; }
  }
  M12 out{};
  for (int i = 0; i < 12; ++i) out.r[i] = v[i];
  return out;
}
constexpr unsigned colq(const M12 m, int q) {
  unsigned c = 0;
  for (int p = 0; p < 12; ++p) c |= ((m.r[p] >> q) & 1u) << p;
  return c;
}
constexpr M12 from_cols(const unsigned (&c)[12]) {
  M12 m{};
  for (int p = 0; p < 12; ++p) {
    unsigned row = 0;
    for (int j = 0; j < 12; ++j) row |= ((c[j] >> p) & 1u) << j;
    m.r[p] = row;
  }
  return m;
}
constexpr M12 mk_id() { M12 m{}; for (int p = 0; p < 12; ++p) m.r[p] = 1u << p; return m; }
constexpr M12 MID = mk_id();
constexpr M12 MPI = minv(MP);

constexpr bool meq(const M12 a, const M12 b) {
  for (int p = 0; p < 12; ++p) if (a.r[p] != b.r[p]) return false;
  return true;
}
static_assert(meq(mmul(MP, MPI), MID), "P inverse");

struct Frame { M12 A, Ai; };
constexpr Frame FID{MID, MID};
constexpr Frame absorb(const Frame f) { return Frame{ mmul(MP, f.A), mmul(f.Ai, MPI) }; }
constexpr Frame apply_tau(const Frame f, const M12 t) {
  return Frame{ mmul(f.A, minv(t)), mmul(t, f.Ai) };
}

// tau with tau(source_i) = target_i AND completion inside the orthogonal
// complement W of the group's role rows -> new frame has CLEAN role rows
// (A'.r[q] == e_target exactly), so the 4 group gates form a wave-uniform
// tensor-product matrix.
constexpr M12 make_tau_W(const Frame f, const int* qs, const unsigned* tg) {
  unsigned S[12] = {}, D[12] = {}, rows[4] = {};
  for (int i = 0; i < 4; ++i) {
    S[i] = colq(f.Ai, qs[i]);
    D[i] = tg[i];
    rows[i] = f.A.r[qs[i]];
  }
  // RREF of the 4 role rows
  unsigned R[4] = {rows[0], rows[1], rows[2], rows[3]};
  int pivcol[4] = {-1, -1, -1, -1};
  int nr = 0;
  for (int c = 0; c < 12 && nr < 4; ++c) {
    int pr = -1;
    for (int r2 = nr; r2 < 4; ++r2) if ((R[r2] >> c) & 1u) { pr = r2; break; }
    if (pr < 0) continue;
    unsigned tmp = R[nr]; R[nr] = R[pr]; R[pr] = tmp;
    for (int r2 = 0; r2 < 4; ++r2)
      if (r2 != nr && ((R[r2] >> c) & 1u)) R[r2] ^= R[nr];
    pivcol[nr] = c; ++nr;
  }
  // null-space basis (8 vectors) of the role-row system
  int cnt = 4;
  for (int j = 0; j < 12; ++j) {
    bool isp = false;
    for (int k = 0; k < nr; ++k) if (pivcol[k] == j) isp = true;
    if (isp) continue;
    unsigned v = 1u << j;
    for (int k = 0; k < nr; ++k) if ((R[k] >> j) & 1u) v |= 1u << pivcol[k];
    S[cnt] = v;
    ++cnt;
  }
  for (int i = 4; i < 12; ++i) D[i] = 1u << i;   // e4..e11
  return mmul(from_cols(D), minv(from_cols(S)));
}
constexpr bool chk_group(const Frame f, const int* qs, const unsigned* tg) {
  for (int i = 0; i < 4; ++i) if (colq(f.Ai, qs[i]) != tg[i]) return false;
  return true;
}

constexpr int QA[4] = {11, 10, 9, 8};
constexpr int QB[4] = {7, 6, 5, 4};
constexpr int QC[4] = {3, 2, 1, 0};
constexpr unsigned T4[4] = {8u, 4u, 2u, 1u};

constexpr Frame F1  = absorb(FID);
constexpr M12  S2a = make_tau_W(F1,  QA, T4);
constexpr Frame F2a = apply_tau(F1, S2a);
constexpr M12  S2b = make_tau_W(F2a, QB, T4);
constexpr Frame F2b = apply_tau(F2a, S2b);
constexpr M12  S2c = make_tau_W(F2b, QC, T4);
constexpr Frame F2c = apply_tau(F2b, S2c);
constexpr Frame F3  = absorb(F2c);
constexpr M12  S3a = make_tau_W(F3,  QA, T4);
constexpr Frame F3a = apply_tau(F3, S3a);
constexpr M12  S3b = make_tau_W(F3a, QB, T4);
constexpr Frame F3b = apply_tau(F3a, S3b);
constexpr M12  S3c = make_tau_W(F3b, QC, T4);
constexpr Frame F3c = apply_tau(F3b, S3c);
constexpr Frame F4  = absorb(F3c);

static_assert(chk_group(F2a, QA, T4), "G2a");
static_assert(chk_group(F2b, QB, T4), "G2b");
static_assert(chk_group(F2c, QC, T4), "G2c");
static_assert(chk_group(F3a, QA, T4), "G3a");
static_assert(chk_group(F3b, QB, T4), "G3b");
static_assert(chk_group(F3c, QC, T4), "G3c");
// clean role rows: gate role == its own local bit (tensor product valid)
static_assert(F2a.A.r[11] == 8u && F2a.A.r[10] == 4u && F2a.A.r[9] == 2u && F2a.A.r[8] == 1u, "rows2a");
static_assert(F2b.A.r[7]  == 8u && F2b.A.r[6]  == 4u && F2b.A.r[5] == 2u && F2b.A.r[4] == 1u, "rows2b");
static_assert(F2c.A.r[3]  == 8u && F2c.A.r[2]  == 4u && F2c.A.r[1] == 2u && F2c.A.r[0] == 1u, "rows2c");
static_assert(F3a.A.r[11] == 8u && F3a.A.r[10] == 4u && F3a.A.r[9] == 2u && F3a.A.r[8] == 1u, "rows3a");
static_assert(F3b.A.r[7]  == 8u && F3b.A.r[6]  == 4u && F3b.A.r[5] == 2u && F3b.A.r[4] == 1u, "rows3b");
static_assert(F3c.A.r[3]  == 8u && F3c.A.r[2]  == 4u && F3c.A.r[1] == 2u && F3c.A.r[0] == 1u, "rows3c");

// ---- LDS layout swizzle B: keyed on index bits [11:5], masks in bits [4:2]
// (keeps b128 4-u32 contiguity: bits 1..0 untouched). Triangular -> bijective.
struct BSw { unsigned mk[7]; };
constexpr unsigned bswap(const BSw& b, unsigned v) {
  unsigned o = v;
  for (int k = 0; k < 7; ++k)
    if ((v >> (5 + k)) & 1u) o ^= b.mk[k];
  return o;
}
constexpr int rank5(const unsigned* v, int n) {
  unsigned basis[5] = {};
  int r = 0;
  for (int i = 0; i < n; ++i) {
    unsigned x = v[i];
    for (int b = 4; b >= 0; --b) {
      if (!((x >> b) & 1u)) continue;
      if (basis[b]) x ^= basis[b];
      else { basis[b] = x; ++r; break; }
    }
  }
  return r;
}
constexpr int readrank(const BSw& b) {   // b128 bank-group bits [4:2]
  unsigned v[5] = { bswap(b, 16u) & 0x1Cu, bswap(b, 32u) & 0x1Cu,
                    bswap(b, 64u) & 0x1Cu, bswap(b, 128u) & 0x1Cu,
                    bswap(b, 8u) & 0x1Cu };
  return rank5(v, 5);
}
constexpr int wrankf(const BSw& b, const unsigned* tv) {  // b32 banks [4:0]
  unsigned v[6] = {};
  for (int k = 0; k < 6; ++k) v[k] = bswap(b, tv[k]) & 0x1Fu;
  return rank5(v, 6);
}
constexpr BSw find_bsw(const M12 T, bool dpass) {
  unsigned src[6] = {16u, 32u, 64u, 128u, dpass ? 4u : 256u, dpass ? 8u : 512u};
  unsigned tv[6] = {};
  for (int k = 0; k < 6; ++k) tv[k] = mv(T, src[k]);
  BSw b{};
  b.mk[0] = 4u;                          // seed: read rank 3 guaranteed
  int bw = wrankf(b, tv);
  for (int s = 0; s < 2; ++s)
    for (int k = 0; k < 7; ++k) {
      unsigned bestv = b.mk[k];
      for (unsigned v = 0; v < 8; ++v) {
        b.mk[k] = v << 2;
        if (readrank(b) < 3) continue;
        const int wr = wrankf(b, tv);
        if (wr > bw) { bw = wr; bestv = v << 2; }
      }
      b.mk[k] = bestv;
    }
  return b;
}
constexpr BSw B0 = find_bsw(S2a, false);
constexpr BSw B1 = find_bsw(S2b, true);
constexpr BSw B2 = find_bsw(S2c, true);
constexpr BSw B3 = find_bsw(S3a, true);
constexpr BSw B4 = find_bsw(S3b, true);
constexpr BSw B5 = find_bsw(S3c, true);
static_assert(readrank(B0) == 3 && readrank(B1) == 3 && readrank(B2) == 3 &&
              readrank(B3) == 3 && readrank(B4) == 3 && readrank(B5) == 3, "rr");

// per-pass runtime tables
struct PT {
  unsigned wc[16];          // write offsets (pass0: local l; else (m<<2)|r)
  unsigned wlb[6], wwb[2];  // write base: lane-bit / wave-bit contributions
  unsigned rlb[5], rwb[2];  // read  base: lane bits 0..3, lane bit4; wave bits
  unsigned rm[2];           // chunk offsets: images of e8, e9
};
constexpr PT mk_pt(const M12 T, const BSw b, bool dpass) {
  PT t{};
  for (int v = 0; v < 16; ++v) {
    const unsigned p = dpass ? ((((unsigned)v >> 2) << 8) | ((unsigned)v & 3u))
                             : (unsigned)v;
    t.wc[v] = bswap(b, mv(T, p));
  }
  unsigned src[6] = {16u, 32u, 64u, 128u, dpass ? 4u : 256u, dpass ? 8u : 512u};
  for (int k = 0; k < 6; ++k) t.wlb[k] = bswap(b, mv(T, src[k]));
  t.wwb[0] = bswap(b, mv(T, 1024u));
  t.wwb[1] = bswap(b, mv(T, 2048u));
  t.rlb[0] = bswap(b, 16u);  t.rlb[1] = bswap(b, 32u);
  t.rlb[2] = bswap(b, 64u);  t.rlb[3] = bswap(b, 128u);
  t.rlb[4] = bswap(b, 8u);
  t.rwb[0] = bswap(b, 1024u); t.rwb[1] = bswap(b, 2048u);
  t.rm[0] = bswap(b, 256u);   t.rm[1] = bswap(b, 512u);
  return t;
}
constexpr PT RT[6] = { mk_pt(S2a, B0, false), mk_pt(S2b, B1, true),
                       mk_pt(S2c, B2, true),  mk_pt(S3a, B3, true),
                       mk_pt(S3b, B4, true),  mk_pt(S3c, B5, true) };

// ================= device helpers =================
template<int PI>
__device__ __forceinline__ unsigned wbase_of(const int lane, const int w) {
  unsigned wb = 0u;
  #pragma unroll
  for (int k = 0; k < 6; ++k) wb ^= ((lane >> k) & 1) ? RT[PI].wlb[k] : 0u;
  wb ^= (w & 1) ? RT[PI].wwb[0] : 0u;
  wb ^= (w & 2) ? RT[PI].wwb[1] : 0u;
  return wb;
}
template<int PI>
__device__ __forceinline__ unsigned rbase_of(const int lane, const int w) {
  unsigned rb = 0u;
  #pragma unroll
  for (int k = 0; k < 4; ++k) rb ^= ((lane >> k) & 1) ? RT[PI].rlb[k] : 0u;
  rb ^= ((lane >> 4) & 1) ? RT[PI].rlb[4] : 0u;
  rb ^= (w & 1) ? RT[PI].rwb[0] : 0u;
  rb ^= (w & 2) ? RT[PI].rwb[1] : 0u;
  return rb;
}

// read B-fragments + 2 MFMAs per chunk.  B[k32][col]: col=lane&15,
// k32=(lane>>4)*8+j  (lane bit5 = im-plane; lanes 32..63 broadcast-read).
template<int PI>
__device__ __forceinline__ void do_pass(f32x4 (&D1)[4], f32x4 (&D2)[4],
                                        const unsigned* sb, const uint4* Am4,
                                        const int lane, const int w,
                                        const unsigned sel) {
  const uint4 a1u = Am4[(PI * 2 + 0) * 64 + lane];
  const uint4 a2u = Am4[(PI * 2 + 1) * 64 + lane];
  const f16x8 A1f = __builtin_bit_cast(f16x8, a1u);
  const f16x8 A2f = __builtin_bit_cast(f16x8, a2u);
  const unsigned rb = rbase_of<PI>(lane, w);
  const f32x4 z4 = {0.f, 0.f, 0.f, 0.f};
  #pragma unroll
  for (int m = 0; m < 4; ++m) {
    const unsigned mo = rb ^ ((m & 1) ? RT[PI].rm[0] : 0u)
                           ^ ((m & 2) ? RT[PI].rm[1] : 0u);
    const uint4 lo = *(const uint4*)(sb + mo);          // amps j=0..3 (h2v)
    const uint4 hi = *(const uint4*)(sb + (mo ^ 4u));   // amps j=4..7
    uint4 bw;
    bw.x = __builtin_amdgcn_perm(lo.y, lo.x, sel);
    bw.y = __builtin_amdgcn_perm(lo.w, lo.z, sel);
    bw.z = __builtin_amdgcn_perm(hi.y, hi.x, sel);
    bw.w = __builtin_amdgcn_perm(hi.w, hi.z, sel);
    const f16x8 Bf = __builtin_bit_cast(f16x8, bw);
    D1[m] = __builtin_amdgcn_mfma_f32_16x16x32_f16(A1f, Bf, z4, 0, 0, 0);
    D2[m] = __builtin_amdgcn_mfma_f32_16x16x32_f16(A2f, Bf, z4, 0, 0, 0);
  }
}

// write state (D layout) into next pass's LDS staging
template<int PI>
__device__ __forceinline__ void write_pass(const f32x4 (&D1)[4],
                                           const f32x4 (&D2)[4],
                                           unsigned* sb, const int lane,
                                           const int w) {
  const unsigned wb = wbase_of<PI>(lane, w);
  h2v* sh = (h2v*)sb;
  #pragma unroll
  for (int m = 0; m < 4; ++m)
    #pragma unroll
    for (int r = 0; r < 4; ++r)
      sh[wb ^ RT[PI].wc[(m << 2) | r]] =
          __builtin_amdgcn_cvt_pkrtz(D1[m][r], D2[m][r]);
}

// gate entry G=[[(gr,gi),(-hr,hi)],[(hr,hi),(gr,-gi)]], g=(gr,gi,hr,hi)
__device__ __forceinline__ void gentry(const float4 g, const int rb,
                                       const int kb, float& re, float& im) {
  re = rb ? (kb ? g.x : g.z) : (kb ? -g.z : g.x);
  im = rb ? (kb ? -g.y : g.w) : (kb ? g.w : g.y);
}

// ================= kernel: one sample per 256-thread block =================
__global__ __launch_bounds__(BLK, 4) void qsim_kernel(
    const float* __restrict__ sr, const float* __restrict__ si,
    const float* __restrict__ wts, const float* __restrict__ hw,
    const float* __restrict__ hb, float* __restrict__ out) {
  __shared__ __align__(16) unsigned sbuf[4096];   // 16 KB f16x2 staging
  __shared__ __align__(16) unsigned Amat[3072];   // 12 KB A-fragments
  __shared__ float4 gt4[24];
  __shared__ float4 qv[12];
  __shared__ float xacc[4];

  const int t = threadIdx.x;
  const int lane = t & 63;
  const int w = t >> 6;                 // position bits 11..10
  const int s = blockIdx.x;

  // Phase A: fused gate table (ref layers 1,2): g=g00, h=g10
  if (t < 24) {
    const int l = 1 + t / 12, i = t % 12;
    const float a  = wts[(l * 12 + i) * 2 + 0] * 0.5f;
    const float bb = wts[(l * 12 + i) * 2 + 1] * 0.5f;
    float sa, ca, sb2, cb;
    sincosf(a, &sa, &ca);
    sincosf(bb, &sb2, &cb);
    gt4[t] = make_float4(cb * ca, sb2 * sa, sb2 * ca, -cb * sa);
  }
  // Phase B: per-wire vectors q_i = G_layer0 * RY(a)RX(a)|0>
  if (t >= 64 && t < 76) {
    const int i = t - 64;
    const float ang = atan2f(si[(size_t)s * 4096 + i],
                             sr[(size_t)s * 4096 + i]) * 0.5f;
    float sn, cs;
    sincosf(ang, &sn, &cs);
    const float e0r = cs * cs, e0i = sn * sn, e1r = sn * cs, e1i = -sn * cs;
    const float a  = wts[i * 2 + 0] * 0.5f;
    const float bb = wts[i * 2 + 1] * 0.5f;
    float sa, ca, sb2, cb;
    sincosf(a, &sa, &ca);
    sincosf(bb, &sb2, &cb);
    const float g00r = cb * ca,  g00i = sb2 * sa, g01r = -sb2 * ca, g01i = -cb * sa;
    const float g10r = sb2 * ca, g10i = -cb * sa, g11r = cb * ca,   g11i = -sb2 * sa;
    const float q0r = g00r * e0r - g00i * e0i + g01r * e1r - g01i * e1i;
    const float q0i = g00r * e0i + g00i * e0r + g01r * e1i + g01i * e1r;
    const float q1r = g10r * e0r - g10i * e0i + g11r * e1r - g11i * e1i;
    const float q1i = g10r * e0i + g10i * e0r + g11r * e1i + g11i * e1r;
    qv[i] = make_float4(q0r, q0i, q1r, q1i);
  }
  __syncthreads();

  // ---- Amat build: M = G(b3)xG(b2)xG(b1)xG(b0) per pass; A1=[Mr|-Mi], A2=[Mi|Mr]
  // layout: lane lw: row=lw&15, k32=(lw>>4)*8+j, j=0..7  (f16 pairs -> u32)
  #pragma unroll
  for (int rep = 0; rep < 3; ++rep) {
    const int idx = t + rep * BLK;        // 0..767 = (pass, mat, lane)
    const int pass = idx >> 7;
    const int mat  = (idx >> 6) & 1;
    const int lw   = idx & 63;
    const int r    = lw & 15;
    const int ks   = lw >> 4;
    const int imf  = ks >> 1;             // k32 bit4 = im half
    const float4 g0 = gt4[pass * 4 + 0];  // acts on bit3
    const float4 g1 = gt4[pass * 4 + 1];  // bit2
    const float4 g2 = gt4[pass * 4 + 2];  // bit1
    const float4 g3 = gt4[pass * 4 + 3];  // bit0
    float b3r, b3i;
    gentry(g0, (r >> 3) & 1, ks & 1, b3r, b3i);   // kpos bit3 = ks bit0
    float t2r[2], t2i[2];
    #pragma unroll
    for (int k2 = 0; k2 < 2; ++k2) {
      float cr, ci;
      gentry(g1, (r >> 2) & 1, k2, cr, ci);
      t2r[k2] = b3r * cr - b3i * ci;
      t2i[k2] = b3r * ci + b3i * cr;
    }
    float t1r[4], t1i[4];
    #pragma unroll
    for (int k2 = 0; k2 < 2; ++k2)
      #pragma unroll
      for (int k1 = 0; k1 < 2; ++k1) {
        float cr, ci;
        gentry(g2, (r >> 1) & 1, k1, cr, ci);
        t1r[k2 * 2 + k1] = t2r[k2] * cr - t2i[k2] * ci;
        t1i[k2 * 2 + k1] = t2r[k2] * ci + t2i[k2] * cr;
      }
    float ev[8];
    #pragma unroll
    for (int j = 0; j < 8; ++j) {
      float cr, ci;
      gentry(g3, r & 1, j & 1, cr, ci);
      const int h2 = j >> 1;
      const float er = t1r[h2] * cr - t1i[h2] * ci;
      const float ei = t1r[h2] * ci + t1i[h2] * cr;
      ev[j] = (mat == 0) ? (imf ? -ei : er) : (imf ? er : ei);
    }
    const int base = ((pass * 2 + mat) * 64 + lw) * 4;
    #pragma unroll
    for (int q = 0; q < 4; ++q) {
      const h2v pk = __builtin_amdgcn_cvt_pkrtz(ev[2 * q], ev[2 * q + 1]);
      Amat[base + q] = __builtin_bit_cast(unsigned, pk);
    }
  }

  // Phase C: product state (F1 frame): wire0<->bit11, wire1<->bit10,
  // wires2-7<->lane bits 5..0, wires8-11<->local bits 3..0.
  float ar[16], ai[16];
  {
    const float4* q = qv;
    float Lr, Li;
    { const float4 q0 = q[0]; const int b0 = (w >> 1) & 1;
      Lr = b0 ? q0.z : q0.x; Li = b0 ? q0.w : q0.y; }
    { const float4 q1 = q[1]; const int b1 = w & 1;
      const float fr = b1 ? q1.z : q1.x, fi = b1 ? q1.w : q1.y;
      const float nr = Lr * fr - Li * fi, ni = Lr * fi + Li * fr;
      Lr = nr; Li = ni; }
    #pragma unroll
    for (int i = 2; i <= 7; ++i) {
      const float4 qq = q[i];
      const int bit = (lane >> (7 - i)) & 1;
      const float fr = bit ? qq.z : qq.x, fi = bit ? qq.w : qq.y;
      const float nr = Lr * fr - Li * fi, ni = Lr * fi + Li * fr;
      Lr = nr; Li = ni;
    }
    float LTr[4], LTi[4];
    { const float4 q8 = q[8], q9 = q[9];
      #pragma unroll
      for (int m = 0; m < 4; ++m) {
        const float xr2 = (m & 2) ? q8.z : q8.x, xi2 = (m & 2) ? q8.w : q8.y;
        const float yr = (m & 1) ? q9.z : q9.x, yi = (m & 1) ? q9.w : q9.y;
        const float tr = xr2 * yr - xi2 * yi, ti = xr2 * yi + xi2 * yr;
        LTr[m] = Lr * tr - Li * ti;
        LTi[m] = Lr * ti + Li * tr;
      } }
    float tbr[4], tbi[4];
    { const float4 qA = q[10], qB2 = q[11];
      #pragma unroll
      for (int m = 0; m < 4; ++m) {
        const float xr2 = (m & 2) ? qA.z : qA.x, xi2 = (m & 2) ? qA.w : qA.y;
        const float yr = (m & 1) ? qB2.z : qB2.x, yi = (m & 1) ? qB2.w : qB2.y;
        tbr[m] = xr2 * yr - xi2 * yi;
        tbi[m] = xr2 * yi + xi2 * yr;
      } }
    #pragma unroll
    for (int l = 0; l < 16; ++l) {
      ar[l] = LTr[l >> 2] * tbr[l & 3] - LTi[l >> 2] * tbi[l & 3];
      ai[l] = LTr[l >> 2] * tbi[l & 3] + LTi[l >> 2] * tbr[l & 3];
    }
  }

  // pass-0 write: amps at p=(w<<10)|(lane<<4)|l, relabeled by tau0
  {
    const unsigned wb = wbase_of<0>(lane, w);
    h2v* sh = (h2v*)sbuf;
    #pragma unroll
    for (int l = 0; l < 16; ++l)
      sh[wb ^ RT[0].wc[l]] = __builtin_amdgcn_cvt_pkrtz(ar[l], ai[l]);
  }
  __syncthreads();

  const unsigned sel = (lane & 32) ? 0x07060302u : 0x05040100u;
  const uint4* Am4 = (const uint4*)Amat;
  f32x4 D1[4], D2[4];

  do_pass<0>(D1, D2, sbuf, Am4, lane, w, sel);
  __syncthreads();
  write_pass<1>(D1, D2, sbuf, lane, w);
  __syncthreads();
  do_pass<1>(D1, D2, sbuf, Am4, lane, w, sel);
  __syncthreads();
  write_pass<2>(D1, D2, sbuf, lane, w);
  __syncthreads();
  do_pass<2>(D1, D2, sbuf, Am4, lane, w, sel);
  __syncthreads();
  write_pass<3>(D1, D2, sbuf, lane, w);
  __syncthreads();
  do_pass<3>(D1, D2, sbuf, Am4, lane, w, sel);
  __syncthreads();
  write_pass<4>(D1, D2, sbuf, lane, w);
  __syncthreads();
  do_pass<4>(D1, D2, sbuf, Am4, lane, w, sel);
  __syncthreads();
  write_pass<5>(D1, D2, sbuf, lane, w);
  __syncthreads();
  do_pass<5>(D1, D2, sbuf, Am4, lane, w, sel);

  // measure: y = sum |amp|^2 * w(F4.A * p) + bias.  D layout: p =
  // (w<<10)|(m<<8)|((lane&15)<<4)|(((lane>>4)&3)<<2)|r
  const unsigned pbase = ((unsigned)w << 10) | ((unsigned)(lane & 15) << 4) |
                         ((unsigned)((lane >> 4) & 3) << 2);
  float hp[12];
  #pragma unroll
  for (int i = 0; i < 12; ++i) {
    const unsigned R = F4.A.r[11 - i];
    const float h = hw[i];
    hp[i] = (__popc(pbase & R & 0xCFCu) & 1) ? -h : h;
  }
  float c[16];
  #pragma unroll
  for (int v = 0; v < 16; ++v) c[v] = 0.f;
  #pragma unroll
  for (int i = 0; i < 12; ++i) {
    const unsigned R = F4.A.r[11 - i];
    const int mu = (int)((((R >> 8) & 3u) << 2) | (R & 3u));
    c[mu] += hp[i];
  }
  #pragma unroll
  for (int bb = 1; bb < 16; bb <<= 1)
    #pragma unroll
    for (int v = 0; v < 16; ++v)
      if (!(v & bb)) {
        const float x = c[v], y = c[v | bb];
        c[v] = x + y;
        c[v | bb] = x - y;
      }
  float acc = 0.f;
  #pragma unroll
  for (int m = 0; m < 4; ++m)
    #pragma unroll
    for (int r = 0; r < 4; ++r)
      acc += (D1[m][r] * D1[m][r] + D2[m][r] * D2[m][r]) * c[(m << 2) | r];
  #pragma unroll
  for (int off = 1; off < 64; off <<= 1) acc += __shfl_xor(acc, off, 64);

  if (lane == 0) xacc[w] = acc;
  __syncthreads();
  if (t == 0) out[s] = xacc[0] + xacc[1] + xacc[2] + xacc[3] + hb[0];
}

extern "C" void kernel_launch(void* const* d_in, const int* in_sizes, int n_in,
                              void* d_out, int out_size, void* d_ws, size_t ws_size,
                              hipStream_t stream) {
  const float* sr  = (const float*)d_in[0];
  const float* si  = (const float*)d_in[1];
  const float* wts = (const float*)d_in[2];
  const float* hw  = (const float*)d_in[3];
  const float* hb  = (const float*)d_in[4];
  float* out = (float*)d_out;
  qsim_kernel<<<BATCH, BLK, 0, stream>>>(sr, si, wts, hw, hb, out);
}